// Round 15
// baseline (294.161 us; speedup 1.0000x reference)
//
#include <hip/hip_runtime.h>
#include <hip/hip_bf16.h>

namespace {

constexpr int kB = 32;
constexpr int kS = 2048;
constexpr int kD = 1024;
constexpr int kU = 1024;

constexpr int BM = 256;
constexpr int BN = 256;
constexpr int kKT = kD / 64;                             // 16 K-tiles (BK=64)
constexpr int kMT = (kB * kS) / BM;                      // 256 m-tiles
constexpr int kNT = kU / BN;                             // 4 n-tiles
constexpr size_t kHalf = 16384;                          // 128 rows x 64 bf16
constexpr size_t kTileChunk = 2 * kHalf;                 // 32 KiB (256 rows x 64)
constexpr size_t kPanel = (size_t)kKT * kTileChunk;      // 512 KiB per 256-row panel

// prep grid: h2 first (latency tail hides under conv streaming), then tpose,
// then conv blocks: one block = 16 enc rows staged through LDS.
constexpr int kH2Blocks = (kU / 64) * (kB / 4);          // 128
constexpr int kTpBlocks = (kU / 32) * (kD / 32);         // 1024
constexpr int kConvBlocks = kMT * 2 * 8;                 // 4096 (mt, rh, sub16)
constexpr int kPrepBlocks = kH2Blocks + kTpBlocks + kConvBlocks;

typedef __attribute__((ext_vector_type(8))) short bf16x8;
typedef __attribute__((ext_vector_type(4))) float f32x4;

__device__ __forceinline__ unsigned short f2bf(float x) {
  union { __hip_bfloat16 h; unsigned short u; } c;
  c.h = __float2bfloat16(x);
  return c.u;
}

__device__ __forceinline__ float bf2f(unsigned short u) {
  union { unsigned int i; float f; } c;
  c.i = ((unsigned int)u) << 16;
  return c.f;
}

__device__ __forceinline__ float tanh_fast(float x) {
  float e = __expf(2.0f * x);
  return 1.0f - 2.0f * __builtin_amdgcn_rcpf(e + 1.0f);
}

__device__ __forceinline__ void gload16(const void* g, void* l) {
  __builtin_amdgcn_global_load_lds(
      (const __attribute__((address_space(1))) void*)g,
      (__attribute__((address_space(3))) void*)l, 16, 0, 0);
}

#define MFMA_BF16(a, b, c) __builtin_amdgcn_mfma_f32_16x16x32_bf16((a), (b), (c), 0, 0, 0)

// ---------------- fast path ----------------

// Fused prep:
//   [0, 128):        h2[b][u] = dec@Wh_w + (Whb+Wsb+Wcb)
//   [128, 1152):     Ws_w fp32 [D][U] -> bf16 B^T panel layout
//   [1152, 5248):    enc fp32 -> encT. One block = 16 rows (mt, rh, sub).
//     Reads: full 4KB rows, lane-contiguous float4 (round-14 read pattern
//     was 16B-with-holes at 256B/row per block -> 1.65 TB/s).
//     LDS: 16 rows x 2KB LINEAR (in-writes contiguous; XOR identity
//     (sub*16+lrow)&7 == lrow&7 lets the swizzle live only in the global
//     write address).
//     Writes: per (kt, 8-row group) 1KB covering whole 128B rows.
__global__ __launch_bounds__(256) void prep_kernel(
    const float* __restrict__ enc, unsigned char* __restrict__ encT,
    const float* __restrict__ Wsw, unsigned char* __restrict__ Bt,
    const float* __restrict__ dec, const float* __restrict__ Whw,
    const float* __restrict__ Whb, const float* __restrict__ Wsb,
    const float* __restrict__ Wcb, float* __restrict__ h2) {
  __shared__ __attribute__((aligned(16))) unsigned char sbuf[32768];
  const int bid = blockIdx.x;
  const int t = threadIdx.x;
  if (bid < kH2Blocks) {
    const int u = (bid & 15) * 64 + (t & 63);
    const int b = (bid >> 4) * 4 + (t >> 6);
    float acc = 0.f;
    const float* dh = dec + b * kD;
    #pragma unroll 8
    for (int d = 0; d < kD; ++d) acc += dh[d] * Whw[(size_t)d * kU + u];
    h2[b * kU + u] = acc + Whb[u] + Wsb[u] + Wcb[u];
  } else if (bid < kH2Blocks + kTpBlocks) {
    float (*tile)[33] = (float (*)[33])sbuf;
    const int q = bid - kH2Blocks;
    const int u0 = (q & 31) * 32, d0 = (q >> 5) * 32;
    const int tx = t & 31, ty = t >> 5;  // 32 x 8
    #pragma unroll
    for (int i = 0; i < 4; ++i)
      tile[ty + i * 8][tx] = Wsw[(size_t)(d0 + ty + i * 8) * kU + u0 + tx];
    __syncthreads();
    #pragma unroll
    for (int i = 0; i < 4; ++i) {
      const int u = u0 + ty + i * 8, d = d0 + tx;
      const int nt = u >> 8, gh = (u >> 7) & 1, n = u & 127;
      const int kt = d >> 6, c = d & 63;
      *(unsigned short*)(Bt + (size_t)nt * kPanel + (size_t)kt * kTileChunk +
                         (size_t)gh * kHalf + n * 128 +
                         (((((unsigned)c >> 3) << 4) ^ (((unsigned)n & 7) << 4)) +
                          (c & 7) * 2)) = f2bf(tile[tx][ty + i * 8]);
    }
  } else {
    const int q = bid - kH2Blocks - kTpBlocks;       // (mt, rh, sub)
    const int mt = q >> 4, rh = (q >> 3) & 1, sub = q & 7;
    const int grow0 = mt * 256 + rh * 128 + sub * 16;   // first of 16 enc rows
    // in: row i fully contiguous; LDS linear at i*2048 + t*8
    #pragma unroll 4
    for (int i = 0; i < 16; ++i) {
      float4 v = *(const float4*)(enc + (size_t)(grow0 + i) * kD + t * 4);
      uint2 p;
      p.x = (unsigned)f2bf(v.x) | ((unsigned)f2bf(v.y) << 16);
      p.y = (unsigned)f2bf(v.z) | ((unsigned)f2bf(v.w) << 16);
      *(uint2*)(sbuf + i * 2048 + t * 8) = p;
    }
    __syncthreads();
    // out: unit w = t + 256j; kt = w>>7; lrow = (w&127)>>3; c8 = w&7.
    unsigned char* base = encT + (size_t)mt * kPanel + (size_t)rh * kHalf +
                          (size_t)(sub * 16) * 128;
    #pragma unroll
    for (int j = 0; j < 8; ++j) {
      const int w = t + 256 * j;
      const int kt = w >> 7, rem = w & 127;
      const int lrow = rem >> 3, c8 = rem & 7;
      uint4 v = *(const uint4*)(sbuf + lrow * 2048 + kt * 128 + c8 * 16);
      *(uint4*)(base + (size_t)kt * kTileChunk + lrow * 128 +
                (((unsigned)c8 << 4) ^ (((unsigned)lrow & 7) << 4))) = v;
    }
  }
}

#define READ_A8(AF, ABASE, QR)                                                 \
  _Pragma("unroll")                                                            \
  for (int rfl = 0; rfl < 4; ++rfl) {                                          \
    _Pragma("unroll")                                                          \
    for (int ks = 0; ks < 2; ++ks) {                                           \
      const int row_ = ((QR)*4 + rfl) * 16 + lr;                               \
      AF[rfl][ks] = *(const bf16x8*)((ABASE) + row_ * 128 +                    \
                                     ((ks * 64 + lq * 16) ^ ((lr & 7) << 4))); \
    }                                                                          \
  }

#define READ_B4(BF, BBASE, QC)                                                 \
  _Pragma("unroll")                                                            \
  for (int cfl = 0; cfl < 2; ++cfl) {                                          \
    _Pragma("unroll")                                                          \
    for (int ks = 0; ks < 2; ++ks) {                                           \
      const int row_ = ((QC)*2 + cfl) * 16 + lr;                               \
      BF[cfl][ks] = *(const bf16x8*)((BBASE) + row_ * 128 +                    \
                                     ((ks * 64 + lq * 16) ^ ((lr & 7) << 4))); \
    }                                                                          \
  }

#define MF16(QR, QC, AF, BF)                                                   \
  _Pragma("unroll")                                                            \
  for (int ks = 0; ks < 2; ++ks) {                                             \
    _Pragma("unroll")                                                          \
    for (int rfl = 0; rfl < 4; ++rfl) {                                        \
      _Pragma("unroll")                                                        \
      for (int cfl = 0; cfl < 2; ++cfl)                                        \
        acc[(QR)*4 + rfl][(QC)*2 + cfl] =                                      \
            MFMA_BF16(AF[rfl][ks], BF[cfl][ks], acc[(QR)*4 + rfl][(QC)*2 + cfl]); \
    }                                                                          \
  }

#define STAGE2(GSRC, LDST)                                                     \
  gload16((GSRC) + so0, (LDST) + so0);                                         \
  gload16((GSRC) + so1, (LDST) + so1);

#define FENCE asm volatile("" ::: "memory")
#define BARRIER { FENCE; __builtin_amdgcn_s_barrier(); FENCE; }

// Fused score GEMM (round-8 proven): 256x256 tile, 8 waves, 8-phase schedule;
// vmcnt(4) at P4/P8 only, prologue vmcnt(4)+barrier, clamped idempotent tail.
__global__ __launch_bounds__(512, 1) void score_gemm4_kernel(
    const unsigned char* __restrict__ encT, const unsigned char* __restrict__ Bt,
    const float* __restrict__ h2, const float* __restrict__ pc,
    const float* __restrict__ Wcw, const float* __restrict__ Vw,
    float* __restrict__ scorep) {
  __shared__ __attribute__((aligned(16))) unsigned char lds[131072];

  const int tid = threadIdx.x;
  const int lane = tid & 63;
  const int w = tid >> 6;
  const int lr = lane & 15, lq = lane >> 4;
  const int wm = w >> 2;
  const int wn = w & 3;
  const int g = wn >> 1;

  const int work = (blockIdx.x & 7) * 128 + (blockIdx.x >> 3);
  const int mtile = work >> 2, ntile = work & 3;

  const unsigned char* Ab = encT + (size_t)mtile * kPanel;
  const unsigned char* Bb = Bt + (size_t)ntile * kPanel;
  const int so0 = tid * 16;
  const int so1 = tid * 16 + 8192;

  unsigned char* Ad0 = lds + (size_t)wm * kHalf;
  unsigned char* Ad1 = lds + (2 + wm) * kHalf;
  unsigned char* Bd0 = lds + 65536 + (size_t)g * kHalf + (wn & 1) * 8192;
  unsigned char* Bd1 = lds + 65536 + (2 + g) * kHalf + (wn & 1) * 8192;
  unsigned char* aSlot[2][2] = {{lds, lds + kHalf}, {lds + 2 * kHalf, lds + 3 * kHalf}};
  unsigned char* bSlot[2][2] = {{lds + 65536, lds + 65536 + kHalf},
                                {lds + 65536 + 2 * kHalf, lds + 65536 + 3 * kHalf}};

  f32x4 acc[8][4];
  #pragma unroll
  for (int i = 0; i < 8; ++i)
    #pragma unroll
    for (int j = 0; j < 4; ++j) acc[i][j] = (f32x4){0.f, 0.f, 0.f, 0.f};

  bf16x8 af[4][2], b0[2][2], b1[2][2];

  STAGE2(Bb, bSlot[0][0]);
  STAGE2(Bb + kHalf, bSlot[0][1]);
  STAGE2(Ab, aSlot[0][0]);
  STAGE2(Ab + kHalf, aSlot[0][1]);
  STAGE2(Bb + kTileChunk, bSlot[1][0]);
  STAGE2(Bb + kTileChunk + kHalf, bSlot[1][1]);
  asm volatile("s_waitcnt vmcnt(4)" ::: "memory");
  BARRIER;

  for (int i = 0; i < kKT / 2; ++i) {
    const int t2 = (i < kKT / 2 - 1) ? 2 * i + 2 : 2 * i;
    const int t3 = (i < kKT / 2 - 1) ? 2 * i + 3 : 2 * i;
    const unsigned char* sA1 = Ab + (size_t)(2 * i + 1) * kTileChunk;
    const unsigned char* sA2 = Ab + (size_t)t2 * kTileChunk;
    const unsigned char* sB2 = Bb + (size_t)t2 * kTileChunk;
    const unsigned char* sB3 = Bb + (size_t)t3 * kTileChunk;

    READ_A8(af, Ad0, 0);
    READ_B4(b0, Bd0, 0);
    STAGE2(sA1, aSlot[1][0]);
    BARRIER;
    __builtin_amdgcn_s_setprio(1);
    MF16(0, 0, af, b0);
    __builtin_amdgcn_s_setprio(0);
    BARRIER;

    READ_B4(b1, Bd0, 1);
    STAGE2(sA1 + kHalf, aSlot[1][1]);
    BARRIER;
    __builtin_amdgcn_s_setprio(1);
    MF16(0, 1, af, b1);
    __builtin_amdgcn_s_setprio(0);
    BARRIER;

    READ_A8(af, Ad0, 1);
    STAGE2(sB2, bSlot[0][0]);
    BARRIER;
    __builtin_amdgcn_s_setprio(1);
    MF16(1, 0, af, b0);
    __builtin_amdgcn_s_setprio(0);
    BARRIER;

    STAGE2(sB2 + kHalf, bSlot[0][1]);
    asm volatile("s_waitcnt vmcnt(4)" ::: "memory");
    BARRIER;
    __builtin_amdgcn_s_setprio(1);
    MF16(1, 1, af, b1);
    __builtin_amdgcn_s_setprio(0);
    BARRIER;

    READ_A8(af, Ad1, 0);
    READ_B4(b0, Bd1, 0);
    STAGE2(sA2, aSlot[0][0]);
    BARRIER;
    __builtin_amdgcn_s_setprio(1);
    MF16(0, 0, af, b0);
    __builtin_amdgcn_s_setprio(0);
    BARRIER;

    READ_B4(b1, Bd1, 1);
    STAGE2(sA2 + kHalf, aSlot[0][1]);
    BARRIER;
    __builtin_amdgcn_s_setprio(1);
    MF16(0, 1, af, b1);
    __builtin_amdgcn_s_setprio(0);
    BARRIER;

    READ_A8(af, Ad1, 1);
    STAGE2(sB3, bSlot[1][0]);
    BARRIER;
    __builtin_amdgcn_s_setprio(1);
    MF16(1, 0, af, b0);
    __builtin_amdgcn_s_setprio(0);
    BARRIER;

    STAGE2(sB3 + kHalf, bSlot[1][1]);
    asm volatile("s_waitcnt vmcnt(4)" ::: "memory");
    BARRIER;
    __builtin_amdgcn_s_setprio(1);
    MF16(1, 1, af, b1);
    __builtin_amdgcn_s_setprio(0);
    BARRIER;
  }
  asm volatile("s_waitcnt vmcnt(0)" ::: "memory");

  const int bidx = mtile >> 3;
  float hv[4], wv[4], vv[4];
  #pragma unroll
  for (int cf = 0; cf < 4; ++cf) {
    const int u = ntile * BN + wn * 64 + cf * 16 + lr;
    hv[cf] = h2[bidx * kU + u];
    wv[cf] = Wcw[u];
    vv[cf] = Vw[u];
  }
  float* plane = scorep + (size_t)(ntile * 4 + wn) * (kB * kS);
  #pragma unroll
  for (int rf = 0; rf < 8; ++rf) {
    #pragma unroll
    for (int j = 0; j < 4; ++j) {
      const int r = mtile * BM + wm * 128 + rf * 16 + lq * 4 + j;
      const float pcv = pc[r];
      float partial = 0.f;
      #pragma unroll
      for (int cf = 0; cf < 4; ++cf) {
        const float feat = acc[rf][cf][j] + hv[cf] + pcv * wv[cf];
        partial += tanh_fast(feat) * vv[cf];
      }
      partial += __shfl_xor(partial, 1);
      partial += __shfl_xor(partial, 2);
      partial += __shfl_xor(partial, 4);
      partial += __shfl_xor(partial, 8);
      if (lr == 0) plane[r] = partial;
    }
  }
}

// softmax over S per b, summing the 16 partial-score planes; cov = attn + pc.
__global__ __launch_bounds__(256) void softmax2_kernel(
    const float* __restrict__ scorep, const float* __restrict__ pc,
    float* __restrict__ attn, float* __restrict__ cov) {
  const int b = blockIdx.x, tid = threadIdx.x;
  const int lane = tid & 63, wid = tid >> 6;
  const size_t base = (size_t)b * kS + tid * 8;
  float v[8] = {0.f, 0.f, 0.f, 0.f, 0.f, 0.f, 0.f, 0.f};
  #pragma unroll
  for (int p = 0; p < 16; ++p) {
    const float* s = scorep + (size_t)p * (kB * kS) + base;
    float4 a = *(const float4*)(s);
    float4 c = *(const float4*)(s + 4);
    v[0] += a.x; v[1] += a.y; v[2] += a.z; v[3] += a.w;
    v[4] += c.x; v[5] += c.y; v[6] += c.z; v[7] += c.w;
  }
  float m = v[0];
  #pragma unroll
  for (int i = 1; i < 8; ++i) m = fmaxf(m, v[i]);
  #pragma unroll
  for (int msk = 1; msk < 64; msk <<= 1) m = fmaxf(m, __shfl_xor(m, msk));
  __shared__ float redm[4], reds[4];
  if (lane == 0) redm[wid] = m;
  __syncthreads();
  m = fmaxf(fmaxf(redm[0], redm[1]), fmaxf(redm[2], redm[3]));
  float e[8], sum = 0.f;
  #pragma unroll
  for (int i = 0; i < 8; ++i) { e[i] = __expf(v[i] - m); sum += e[i]; }
  #pragma unroll
  for (int msk = 1; msk < 64; msk <<= 1) sum += __shfl_xor(sum, msk);
  if (lane == 0) reds[wid] = sum;
  __syncthreads();
  sum = reds[0] + reds[1] + reds[2] + reds[3];
  const float inv = 1.0f / sum;
  float pv[8], a[8], c[8];
  const float* p = pc + base;
  *(float4*)(pv) = *(const float4*)(p);
  *(float4*)(pv + 4) = *(const float4*)(p + 4);
  #pragma unroll
  for (int i = 0; i < 8; ++i) { a[i] = e[i] * inv; c[i] = a[i] + pv[i]; }
  *(float4*)(attn + base) = *(float4*)(a);
  *(float4*)(attn + base + 4) = *(float4*)(a + 4);
  *(float4*)(cov + base) = *(float4*)(c);
  *(float4*)(cov + base + 4) = *(float4*)(c + 4);
}

// context from bf16 encT: block = (kt, b); no atomics.
__global__ __launch_bounds__(256) void context2_kernel(
    const unsigned char* __restrict__ encT, const float* __restrict__ attn,
    float* __restrict__ ctx) {
  const int kt = blockIdx.x;
  const int b = blockIdx.y;
  const int cg = threadIdx.x & 7;
  const int rgrp = threadIdx.x >> 3;
  float acc8[8];
  #pragma unroll
  for (int j = 0; j < 8; ++j) acc8[j] = 0.f;
  const float* ab = attn + (size_t)b * kS;
  for (int it = 0; it < kS / 32; ++it) {
    const int s = it * 32 + rgrp;
    const int r = b * kS + s;
    const int mt = r >> 8, rh = (r >> 7) & 1, row = r & 127;
    const unsigned char* chunk = encT + (size_t)mt * kPanel +
                                 (size_t)kt * kTileChunk + (size_t)rh * kHalf;
    uint4 v = *(const uint4*)(chunk + row * 128 +
                              ((((unsigned)cg << 4) ^ (((unsigned)row & 7) << 4))));
    const float a = ab[s];
    const unsigned int* vw = (const unsigned int*)&v;
    #pragma unroll
    for (int q = 0; q < 4; ++q) {
      acc8[2 * q]     += a * bf2f((unsigned short)(vw[q] & 0xffff));
      acc8[2 * q + 1] += a * bf2f((unsigned short)(vw[q] >> 16));
    }
  }
  __shared__ float red[256 * 8];
  #pragma unroll
  for (int j = 0; j < 8; ++j) red[threadIdx.x * 8 + j] = acc8[j];
  __syncthreads();
  for (int stride = 16; stride > 0; stride >>= 1) {
    if (rgrp < stride) {
      #pragma unroll
      for (int j = 0; j < 8; ++j)
        red[(rgrp * 8 + cg) * 8 + j] += red[((rgrp + stride) * 8 + cg) * 8 + j];
    }
    __syncthreads();
  }
  if (rgrp == 0) {
    #pragma unroll
    for (int j = 0; j < 8; ++j)
      ctx[(size_t)b * kD + kt * 64 + cg * 8 + j] = red[cg * 8 + j];
  }
}

// ---------------- fallback path (round-2 proven kernels, small ws) ----------------

__global__ __launch_bounds__(256) void h2b_kernel(
    const float* __restrict__ dec, const float* __restrict__ Whw,
    const float* __restrict__ Whb, const float* __restrict__ Wsb,
    const float* __restrict__ Wcb, float* __restrict__ h2) {
  const int u = blockIdx.x * 64 + (threadIdx.x & 63);
  const int b = blockIdx.y * 4 + (threadIdx.x >> 6);
  float acc = 0.f;
  const float* dh = dec + b * kD;
  #pragma unroll 8
  for (int d = 0; d < kD; ++d) acc += dh[d] * Whw[(size_t)d * kU + u];
  h2[b * kU + u] = acc + Whb[u] + Wsb[u] + Wcb[u];
}

__global__ __launch_bounds__(256) void tpose_fb_kernel(
    const float* __restrict__ W, unsigned short* __restrict__ out) {
  __shared__ float tile[32][33];
  const int u0 = blockIdx.x * 32, d0 = blockIdx.y * 32;
  const int tx = threadIdx.x & 31, ty = threadIdx.x >> 5;
  #pragma unroll
  for (int i = 0; i < 4; ++i)
    tile[ty + i * 8][tx] = W[(size_t)(d0 + ty + i * 8) * kU + u0 + tx];
  __syncthreads();
  #pragma unroll
  for (int i = 0; i < 4; ++i)
    out[(size_t)(u0 + ty + i * 8) * kD + d0 + tx] = f2bf(tile[tx][ty + i * 8]);
}

__global__ __launch_bounds__(256, 2) void score_gemm_fb_kernel(
    const float* __restrict__ enc, const unsigned short* __restrict__ WsT,
    const float* __restrict__ h2, const float* __restrict__ pc,
    const float* __restrict__ Wcw, const float* __restrict__ Vw,
    float* __restrict__ score) {
  __shared__ __attribute__((aligned(16))) unsigned char smA[128 * 64 * 2];
  __shared__ __attribute__((aligned(16))) unsigned char smB[128 * 64 * 2];
  const int tid = threadIdx.x;
  const int lane = tid & 63;
  const int wid = tid >> 6;
  const int wr = wid >> 1, wc = wid & 1;
  const int mtile = blockIdx.x >> 3, ntile = blockIdx.x & 7;
  const int r0 = mtile * 128, n0 = ntile * 128;
  f32x4 acc[4][4];
  #pragma unroll
  for (int i = 0; i < 4; ++i)
    #pragma unroll
    for (int j = 0; j < 4; ++j) acc[i][j] = (f32x4){0.f, 0.f, 0.f, 0.f};
  const int kqA = tid & 15;
  const int rowA = tid >> 4;
  const int kcB = tid & 7;
  const int nB = tid >> 3;
  float4 aReg[8];
  uint4 bReg[4];
  #pragma unroll
  for (int i = 0; i < 8; ++i)
    aReg[i] = *(const float4*)(enc + (size_t)(r0 + rowA + 16 * i) * kD + kqA * 4);
  #pragma unroll
  for (int i = 0; i < 4; ++i)
    bReg[i] = *(const uint4*)(WsT + (size_t)(n0 + nB + 32 * i) * kD + kcB * 8);
  const int lr = lane & 15, lq = lane >> 4;
  for (int k0 = 0; k0 < kD; k0 += 64) {
    #pragma unroll
    for (int i = 0; i < 8; ++i) {
      const int row = rowA + 16 * i;
      uint2 p;
      p.x = (unsigned)f2bf(aReg[i].x) | ((unsigned)f2bf(aReg[i].y) << 16);
      p.y = (unsigned)f2bf(aReg[i].z) | ((unsigned)f2bf(aReg[i].w) << 16);
      *(uint2*)(smA + row * 128 + ((kqA * 8) ^ ((row & 7) << 4))) = p;
    }
    #pragma unroll
    for (int i = 0; i < 4; ++i) {
      const int n = nB + 32 * i;
      *(uint4*)(smB + n * 128 + ((kcB * 16) ^ ((n & 7) << 4))) = bReg[i];
    }
    __syncthreads();
    if (k0 + 64 < kD) {
      const int kn = k0 + 64;
      #pragma unroll
      for (int i = 0; i < 8; ++i)
        aReg[i] = *(const float4*)(enc + (size_t)(r0 + rowA + 16 * i) * kD + kn + kqA * 4);
      #pragma unroll
      for (int i = 0; i < 4; ++i)
        bReg[i] = *(const uint4*)(WsT + (size_t)(n0 + nB + 32 * i) * kD + kn + kcB * 8);
    }
    #pragma unroll
    for (int ks = 0; ks < 2; ++ks) {
      const int kb = ks * 64 + lq * 16;
      bf16x8 af2[4], bfr[4];
      #pragma unroll
      for (int fm = 0; fm < 4; ++fm) {
        const int row = wr * 64 + fm * 16 + lr;
        af2[fm] = *(const bf16x8*)(smA + row * 128 + (kb ^ ((row & 7) << 4)));
      }
      #pragma unroll
      for (int fn = 0; fn < 4; ++fn) {
        const int n = wc * 64 + fn * 16 + lr;
        bfr[fn] = *(const bf16x8*)(smB + n * 128 + (kb ^ ((n & 7) << 4)));
      }
      #pragma unroll
      for (int fm = 0; fm < 4; ++fm)
        #pragma unroll
        for (int fn = 0; fn < 4; ++fn)
          acc[fm][fn] = MFMA_BF16(af2[fm], bfr[fn], acc[fm][fn]);
    }
    __syncthreads();
  }
  const int bidx = r0 >> 11;
  float hv[4], wv[4], vv[4];
  #pragma unroll
  for (int fn = 0; fn < 4; ++fn) {
    const int u = n0 + wc * 64 + fn * 16 + lr;
    hv[fn] = h2[bidx * kU + u];
    wv[fn] = Wcw[u];
    vv[fn] = Vw[u];
  }
  #pragma unroll
  for (int fm = 0; fm < 4; ++fm) {
    #pragma unroll
    for (int j = 0; j < 4; ++j) {
      const int r = r0 + wr * 64 + fm * 16 + lq * 4 + j;
      const float pcv = pc[r];
      float partial = 0.f;
      #pragma unroll
      for (int fn = 0; fn < 4; ++fn) {
        const float feat = acc[fm][fn][j] + hv[fn] + pcv * wv[fn];
        partial += tanh_fast(feat) * vv[fn];
      }
      partial += __shfl_xor(partial, 1);
      partial += __shfl_xor(partial, 2);
      partial += __shfl_xor(partial, 4);
      partial += __shfl_xor(partial, 8);
      if (lr == 0) atomicAdd(&score[r], partial);
    }
  }
}

__global__ __launch_bounds__(256) void softmax_fb_kernel(
    const float* __restrict__ score, const float* __restrict__ pc,
    float* __restrict__ attn, float* __restrict__ cov) {
  const int b = blockIdx.x, tid = threadIdx.x;
  const int lane = tid & 63, wid = tid >> 6;
  const float* s = score + (size_t)b * kS;
  float v[8];
  *(float4*)(v) = *(const float4*)(s + tid * 8);
  *(float4*)(v + 4) = *(const float4*)(s + tid * 8 + 4);
  float m = v[0];
  #pragma unroll
  for (int i = 1; i < 8; ++i) m = fmaxf(m, v[i]);
  #pragma unroll
  for (int msk = 1; msk < 64; msk <<= 1) m = fmaxf(m, __shfl_xor(m, msk));
  __shared__ float redm[4], reds[4];
  if (lane == 0) redm[wid] = m;
  __syncthreads();
  m = fmaxf(fmaxf(redm[0], redm[1]), fmaxf(redm[2], redm[3]));
  float e[8], sum = 0.f;
  #pragma unroll
  for (int i = 0; i < 8; ++i) { e[i] = __expf(v[i] - m); sum += e[i]; }
  #pragma unroll
  for (int msk = 1; msk < 64; msk <<= 1) sum += __shfl_xor(sum, msk);
  if (lane == 0) reds[wid] = sum;
  __syncthreads();
  sum = reds[0] + reds[1] + reds[2] + reds[3];
  const float inv = 1.0f / sum;
  float pv[8], a[8], c[8];
  const float* p = pc + (size_t)b * kS + tid * 8;
  *(float4*)(pv) = *(const float4*)(p);
  *(float4*)(pv + 4) = *(const float4*)(p + 4);
  #pragma unroll
  for (int i = 0; i < 8; ++i) { a[i] = e[i] * inv; c[i] = a[i] + pv[i]; }
  *(float4*)(attn + (size_t)b * kS + tid * 8) = *(float4*)(a);
  *(float4*)(attn + (size_t)b * kS + tid * 8 + 4) = *(float4*)(a + 4);
  *(float4*)(cov + (size_t)b * kS + tid * 8) = *(float4*)(c);
  *(float4*)(cov + (size_t)b * kS + tid * 8 + 4) = *(float4*)(c + 4);
}

__global__ __launch_bounds__(256) void context_fb_kernel(
    const float* __restrict__ enc, const float* __restrict__ attn,
    float* __restrict__ ctx) {
  const int b = blockIdx.z;
  const int s0 = blockIdx.y * 256;
  const int d = blockIdx.x * 256 + threadIdx.x;
  const float* e = enc + ((size_t)b * kS + s0) * kD + d;
  const float* a = attn + (size_t)b * kS + s0;
  float acc = 0.f;
  #pragma unroll 8
  for (int s = 0; s < 256; ++s) acc += a[s] * e[(size_t)s * kD];
  atomicAdd(&ctx[b * kD + d], acc);
}

}  // namespace

extern "C" void kernel_launch(void* const* d_in, const int* in_sizes, int n_in,
                              void* d_out, int out_size, void* d_ws, size_t ws_size,
                              hipStream_t stream) {
  (void)in_sizes; (void)n_in; (void)out_size;
  const float* dec = (const float*)d_in[0];
  const float* enc = (const float*)d_in[1];
  const float* pc  = (const float*)d_in[4];
  const float* Wsw = (const float*)d_in[5];
  const float* Wsb = (const float*)d_in[6];
  const float* Whw = (const float*)d_in[7];
  const float* Whb = (const float*)d_in[8];
  const float* Wcw = (const float*)d_in[9];
  const float* Wcb = (const float*)d_in[10];
  const float* Vw  = (const float*)d_in[11];

  float* ctx  = (float*)d_out;             // [B, D]
  float* attn = (float*)d_out + kB * kD;   // [B, S]
  float* cov  = attn + kB * kS;            // [B, S, 1]

  unsigned char* ws = (unsigned char*)d_ws;

  const size_t encT_sz = (size_t)kB * kS * kD * 2;   // 128 MiB
  const size_t Bt_sz   = (size_t)kU * kD * 2;        // 2 MiB
  const size_t h2_sz   = (size_t)kB * kU * 4;        // 128 KiB
  const size_t sp_sz   = (size_t)16 * kB * kS * 4;   // 4 MiB
  const size_t need    = encT_sz + Bt_sz + h2_sz + sp_sz;

  if (ws_size >= need) {
    unsigned char* encT = ws;
    unsigned char* Bt   = ws + encT_sz;
    float* h2     = (float*)(ws + encT_sz + Bt_sz);
    float* scorep = (float*)(ws + encT_sz + Bt_sz + h2_sz);

    prep_kernel<<<dim3(kPrepBlocks), 256, 0, stream>>>(
        enc, encT, Wsw, Bt, dec, Whw, Whb, Wsb, Wcb, h2);
    score_gemm4_kernel<<<dim3(kMT * kNT), 512, 0, stream>>>(
        encT, Bt, h2, pc, Wcw, Vw, scorep);
    softmax2_kernel<<<dim3(kB), 256, 0, stream>>>(scorep, pc, attn, cov);
    context2_kernel<<<dim3(kD / 64, kB), 256, 0, stream>>>(encT, attn, ctx);
  } else {
    unsigned short* WsT = (unsigned short*)ws;                       // 2 MiB
    float* h2    = (float*)(ws + (size_t)2 * 1024 * 1024);           // 128 KiB
    float* score = (float*)(ws + (size_t)2 * 1024 * 1024 + 131072);  // 256 KiB
    hipMemsetAsync(score, 0, kB * kS * sizeof(float), stream);
    hipMemsetAsync(ctx, 0, kB * kD * sizeof(float), stream);
    h2b_kernel<<<dim3(kU / 64, kB / 4), 256, 0, stream>>>(dec, Whw, Whb, Wsb, Wcb, h2);
    tpose_fb_kernel<<<dim3(kU / 32, kD / 32), 256, 0, stream>>>(Wsw, WsT);
    score_gemm_fb_kernel<<<dim3(4096), 256, 0, stream>>>(
        enc, WsT, h2, pc, Wcw, Vw, score);
    softmax_fb_kernel<<<dim3(kB), 256, 0, stream>>>(score, pc, attn, cov);
    context_fb_kernel<<<dim3(kD / 256, kS / 256, kB), 256, 0, stream>>>(enc, attn, ctx);
  }
}

// Round 16
// 291.351 us; speedup vs baseline: 1.0096x; 1.0096x over previous
//
#include <hip/hip_runtime.h>
#include <hip/hip_bf16.h>

namespace {

constexpr int kB = 32;
constexpr int kS = 2048;
constexpr int kD = 1024;
constexpr int kU = 1024;

constexpr int BM = 256;
constexpr int BN = 256;
constexpr int kKT = kD / 64;                             // 16 K-tiles (BK=64)
constexpr int kMT = (kB * kS) / BM;                      // 256 m-tiles
constexpr int kNT = kU / BN;                             // 4 n-tiles
constexpr size_t kHalf = 16384;                          // 128 rows x 64 bf16
constexpr size_t kTileChunk = 2 * kHalf;                 // 32 KiB
constexpr size_t kPanel = (size_t)kKT * kTileChunk;      // 512 KiB (B panels only)

// prep: h2 first (latency tail hides under conv streaming), tpose, then
// pure-streaming row-major bf16 conversion of enc.
constexpr int kH2Blocks = (kU / 64) * (kB / 4);          // 128
constexpr int kTpBlocks = (kU / 32) * (kD / 32);         // 1024
constexpr int kConvBlocks = (kB * kS * kD / 8) / 256;    // 32768
constexpr int kPrepBlocks = kH2Blocks + kTpBlocks + kConvBlocks;

typedef __attribute__((ext_vector_type(8))) short bf16x8;
typedef __attribute__((ext_vector_type(4))) float f32x4;

__device__ __forceinline__ unsigned short f2bf(float x) {
  union { __hip_bfloat16 h; unsigned short u; } c;
  c.h = __float2bfloat16(x);
  return c.u;
}

__device__ __forceinline__ float bf2f(unsigned short u) {
  union { unsigned int i; float f; } c;
  c.i = ((unsigned int)u) << 16;
  return c.f;
}

__device__ __forceinline__ float tanh_fast(float x) {
  float e = __expf(2.0f * x);
  return 1.0f - 2.0f * __builtin_amdgcn_rcpf(e + 1.0f);
}

__device__ __forceinline__ void gload16(const void* g, void* l) {
  __builtin_amdgcn_global_load_lds(
      (const __attribute__((address_space(1))) void*)g,
      (__attribute__((address_space(3))) void*)l, 16, 0, 0);
}

#define MFMA_BF16(a, b, c) __builtin_amdgcn_mfma_f32_16x16x32_bf16((a), (b), (c), 0, 0, 0)

// ---------------- fast path ----------------

// Fused prep:
//   [0, 128):        h2[b][u] = dec@Wh_w + (Whb+Wsb+Wcb)
//   [128, 1152):     Ws_w fp32 [D][U] -> bf16 B^T panel layout (tiny)
//   [1152, 33920):   enc fp32 -> encR bf16 ROW-MAJOR, pure streaming:
//                    contiguous reads (32B/lane) and writes (16B/lane),
//                    no LDS, no swizzle. The GEMM-ready permutation lives
//                    in the GEMM's per-lane gload_lds SOURCE addresses
//                    (m173 pattern) instead of in memory.
__global__ __launch_bounds__(256) void prep_kernel(
    const float* __restrict__ enc, unsigned char* __restrict__ encR,
    const float* __restrict__ Wsw, unsigned char* __restrict__ Bt,
    const float* __restrict__ dec, const float* __restrict__ Whw,
    const float* __restrict__ Whb, const float* __restrict__ Wsb,
    const float* __restrict__ Wcb, float* __restrict__ h2) {
  __shared__ float tile[32][33];
  const int bid = blockIdx.x;
  const int t = threadIdx.x;
  if (bid < kH2Blocks) {
    const int u = (bid & 15) * 64 + (t & 63);
    const int b = (bid >> 4) * 4 + (t >> 6);
    float acc = 0.f;
    const float* dh = dec + b * kD;
    #pragma unroll 8
    for (int d = 0; d < kD; ++d) acc += dh[d] * Whw[(size_t)d * kU + u];
    h2[b * kU + u] = acc + Whb[u] + Wsb[u] + Wcb[u];
  } else if (bid < kH2Blocks + kTpBlocks) {
    const int q = bid - kH2Blocks;
    const int u0 = (q & 31) * 32, d0 = (q >> 5) * 32;
    const int tx = t & 31, ty = t >> 5;  // 32 x 8
    #pragma unroll
    for (int i = 0; i < 4; ++i)
      tile[ty + i * 8][tx] = Wsw[(size_t)(d0 + ty + i * 8) * kU + u0 + tx];
    __syncthreads();
    #pragma unroll
    for (int i = 0; i < 4; ++i) {
      const int u = u0 + ty + i * 8, d = d0 + tx;
      const int nt = u >> 8, gh = (u >> 7) & 1, n = u & 127;
      const int kt = d >> 6, c = d & 63;
      *(unsigned short*)(Bt + (size_t)nt * kPanel + (size_t)kt * kTileChunk +
                         (size_t)gh * kHalf + n * 128 +
                         (((((unsigned)c >> 3) << 4) ^ (((unsigned)n & 7) << 4)) +
                          (c & 7) * 2)) = f2bf(tile[tx][ty + i * 8]);
    }
  } else {
    const size_t e = ((size_t)(bid - kH2Blocks - kTpBlocks) * 256 + t) * 8;
    float4 v0 = *(const float4*)(enc + e);
    float4 v1 = *(const float4*)(enc + e + 4);
    uint4 p;
    p.x = (unsigned)f2bf(v0.x) | ((unsigned)f2bf(v0.y) << 16);
    p.y = (unsigned)f2bf(v0.z) | ((unsigned)f2bf(v0.w) << 16);
    p.z = (unsigned)f2bf(v1.x) | ((unsigned)f2bf(v1.y) << 16);
    p.w = (unsigned)f2bf(v1.z) | ((unsigned)f2bf(v1.w) << 16);
    *(uint4*)(encR + e * 2) = p;
  }
}

#define READ_A8(AF, ABASE, QR)                                                 \
  _Pragma("unroll")                                                            \
  for (int rfl = 0; rfl < 4; ++rfl) {                                          \
    _Pragma("unroll")                                                          \
    for (int ks = 0; ks < 2; ++ks) {                                           \
      const int row_ = ((QR)*4 + rfl) * 16 + lr;                               \
      AF[rfl][ks] = *(const bf16x8*)((ABASE) + row_ * 128 +                    \
                                     ((ks * 64 + lq * 16) ^ ((lr & 7) << 4))); \
    }                                                                          \
  }

#define READ_B4(BF, BBASE, QC)                                                 \
  _Pragma("unroll")                                                            \
  for (int cfl = 0; cfl < 2; ++cfl) {                                          \
    _Pragma("unroll")                                                          \
    for (int ks = 0; ks < 2; ++ks) {                                           \
      const int row_ = ((QC)*2 + cfl) * 16 + lr;                               \
      BF[cfl][ks] = *(const bf16x8*)((BBASE) + row_ * 128 +                    \
                                     ((ks * 64 + lq * 16) ^ ((lr & 7) << 4))); \
    }                                                                          \
  }

#define MF16(QR, QC, AF, BF)                                                   \
  _Pragma("unroll")                                                            \
  for (int ks = 0; ks < 2; ++ks) {                                             \
    _Pragma("unroll")                                                          \
    for (int rfl = 0; rfl < 4; ++rfl) {                                        \
      _Pragma("unroll")                                                        \
      for (int cfl = 0; cfl < 2; ++cfl)                                        \
        acc[(QR)*4 + rfl][(QC)*2 + cfl] =                                      \
            MFMA_BF16(AF[rfl][ks], BF[cfl][ks], acc[(QR)*4 + rfl][(QC)*2 + cfl]); \
    }                                                                          \
  }

// B stage: panel layout, linear per-thread slice (unchanged).
#define STAGE2(GSRC, LDST)                                                     \
  gload16((GSRC) + so0, (LDST) + so0);                                         \
  gload16((GSRC) + so1, (LDST) + so1);

// A stage from ROW-MAJOR encR: per-lane pre-swizzled source. Lane tid's 16B
// for LDS linear offset tid*16 is row-major (row = tid>>3, c8 = (tid&7) ^
// (row&7)) -- reproduces the old panel bytes exactly. Rows +64 (so1) and
// +128 (half) keep the XOR (64,128 == 0 mod 8). K-tile t = +t*128 bytes.
// Each 8-lane group covers one full 128B line -> coalesced. 2 gload16 per
// call, same as STAGE2 -> vmcnt accounting identical.
#define STAGEA(T, H, LDST)                                                     \
  gload16(Asrc + (size_t)(T) * 128 + (size_t)(H) * 262144, (LDST) + so0);      \
  gload16(Asrc + (size_t)(T) * 128 + (size_t)(H) * 262144 + 131072,            \
          (LDST) + so1);

#define FENCE asm volatile("" ::: "memory")
#define BARRIER { FENCE; __builtin_amdgcn_s_barrier(); FENCE; }

// Fused score GEMM (round-8 proven schedule, A-source re-addressed to
// row-major): 256x256 tile, 8 waves, 8-phase; vmcnt(4) at P4/P8 only,
// prologue vmcnt(4)+barrier, clamped idempotent tail.
__global__ __launch_bounds__(512, 1) void score_gemm4_kernel(
    const unsigned char* __restrict__ encR, const unsigned char* __restrict__ Bt,
    const float* __restrict__ h2, const float* __restrict__ pc,
    const float* __restrict__ Wcw, const float* __restrict__ Vw,
    float* __restrict__ scorep) {
  __shared__ __attribute__((aligned(16))) unsigned char lds[131072];

  const int tid = threadIdx.x;
  const int lane = tid & 63;
  const int w = tid >> 6;
  const int lr = lane & 15, lq = lane >> 4;
  const int wm = w >> 2;
  const int wn = w & 3;
  const int g = wn >> 1;

  const int work = (blockIdx.x & 7) * 128 + (blockIdx.x >> 3);
  const int mtile = work >> 2, ntile = work & 3;

  // per-lane pre-swizzled A source base (row-major, 2048 B/row)
  const int arow = tid >> 3;
  const unsigned char* Asrc = encR + (size_t)mtile * 524288 +
                              (size_t)arow * 2048 +
                              (size_t)(((tid & 7) ^ (arow & 7)) * 16);
  const unsigned char* Bb = Bt + (size_t)ntile * kPanel;
  const int so0 = tid * 16;
  const int so1 = tid * 16 + 8192;

  unsigned char* Ad0 = lds + (size_t)wm * kHalf;
  unsigned char* Ad1 = lds + (2 + wm) * kHalf;
  unsigned char* Bd0 = lds + 65536 + (size_t)g * kHalf + (wn & 1) * 8192;
  unsigned char* Bd1 = lds + 65536 + (2 + g) * kHalf + (wn & 1) * 8192;
  unsigned char* aSlot[2][2] = {{lds, lds + kHalf}, {lds + 2 * kHalf, lds + 3 * kHalf}};
  unsigned char* bSlot[2][2] = {{lds + 65536, lds + 65536 + kHalf},
                                {lds + 65536 + 2 * kHalf, lds + 65536 + 3 * kHalf}};

  f32x4 acc[8][4];
  #pragma unroll
  for (int i = 0; i < 8; ++i)
    #pragma unroll
    for (int j = 0; j < 4; ++j) acc[i][j] = (f32x4){0.f, 0.f, 0.f, 0.f};

  bf16x8 af[4][2], b0[2][2], b1[2][2];

  // ---- prologue: B(t0), A(t0) h0/h1, B(t1); vmcnt(4) -> t0 landed ----
  STAGE2(Bb, bSlot[0][0]);
  STAGE2(Bb + kHalf, bSlot[0][1]);
  STAGEA(0, 0, aSlot[0][0]);
  STAGEA(0, 1, aSlot[0][1]);
  STAGE2(Bb + kTileChunk, bSlot[1][0]);
  STAGE2(Bb + kTileChunk + kHalf, bSlot[1][1]);
  asm volatile("s_waitcnt vmcnt(4)" ::: "memory");
  BARRIER;

  for (int i = 0; i < kKT / 2; ++i) {
    const int t1 = 2 * i + 1;
    const int t2 = (i < kKT / 2 - 1) ? 2 * i + 2 : 2 * i;      // clamped tail
    const int t3 = (i < kKT / 2 - 1) ? 2 * i + 3 : 2 * i;
    const unsigned char* sB2 = Bb + (size_t)t2 * kTileChunk;
    const unsigned char* sB3 = Bb + (size_t)t3 * kTileChunk;

    // ---- P1
    READ_A8(af, Ad0, 0);
    READ_B4(b0, Bd0, 0);
    STAGEA(t1, 0, aSlot[1][0]);
    BARRIER;
    __builtin_amdgcn_s_setprio(1);
    MF16(0, 0, af, b0);
    __builtin_amdgcn_s_setprio(0);
    BARRIER;

    // ---- P2
    READ_B4(b1, Bd0, 1);
    STAGEA(t1, 1, aSlot[1][1]);
    BARRIER;
    __builtin_amdgcn_s_setprio(1);
    MF16(0, 1, af, b1);
    __builtin_amdgcn_s_setprio(0);
    BARRIER;

    // ---- P3
    READ_A8(af, Ad0, 1);
    STAGE2(sB2, bSlot[0][0]);
    BARRIER;
    __builtin_amdgcn_s_setprio(1);
    MF16(1, 0, af, b0);
    __builtin_amdgcn_s_setprio(0);
    BARRIER;

    // ---- P4
    STAGE2(sB2 + kHalf, bSlot[0][1]);
    asm volatile("s_waitcnt vmcnt(4)" ::: "memory");
    BARRIER;
    __builtin_amdgcn_s_setprio(1);
    MF16(1, 1, af, b1);
    __builtin_amdgcn_s_setprio(0);
    BARRIER;

    // ---- P5
    READ_A8(af, Ad1, 0);
    READ_B4(b0, Bd1, 0);
    STAGEA(t2, 0, aSlot[0][0]);
    BARRIER;
    __builtin_amdgcn_s_setprio(1);
    MF16(0, 0, af, b0);
    __builtin_amdgcn_s_setprio(0);
    BARRIER;

    // ---- P6
    READ_B4(b1, Bd1, 1);
    STAGEA(t2, 1, aSlot[0][1]);
    BARRIER;
    __builtin_amdgcn_s_setprio(1);
    MF16(0, 1, af, b1);
    __builtin_amdgcn_s_setprio(0);
    BARRIER;

    // ---- P7
    READ_A8(af, Ad1, 1);
    STAGE2(sB3, bSlot[1][0]);
    BARRIER;
    __builtin_amdgcn_s_setprio(1);
    MF16(1, 0, af, b0);
    __builtin_amdgcn_s_setprio(0);
    BARRIER;

    // ---- P8
    STAGE2(sB3 + kHalf, bSlot[1][1]);
    asm volatile("s_waitcnt vmcnt(4)" ::: "memory");
    BARRIER;
    __builtin_amdgcn_s_setprio(1);
    MF16(1, 1, af, b1);
    __builtin_amdgcn_s_setprio(0);
    BARRIER;
  }
  asm volatile("s_waitcnt vmcnt(0)" ::: "memory");

  const int bidx = mtile >> 3;
  float hv[4], wv[4], vv[4];
  #pragma unroll
  for (int cf = 0; cf < 4; ++cf) {
    const int u = ntile * BN + wn * 64 + cf * 16 + lr;
    hv[cf] = h2[bidx * kU + u];
    wv[cf] = Wcw[u];
    vv[cf] = Vw[u];
  }
  float* plane = scorep + (size_t)(ntile * 4 + wn) * (kB * kS);
  #pragma unroll
  for (int rf = 0; rf < 8; ++rf) {
    #pragma unroll
    for (int j = 0; j < 4; ++j) {
      const int r = mtile * BM + wm * 128 + rf * 16 + lq * 4 + j;
      const float pcv = pc[r];
      float partial = 0.f;
      #pragma unroll
      for (int cf = 0; cf < 4; ++cf) {
        const float feat = acc[rf][cf][j] + hv[cf] + pcv * wv[cf];
        partial += tanh_fast(feat) * vv[cf];
      }
      partial += __shfl_xor(partial, 1);
      partial += __shfl_xor(partial, 2);
      partial += __shfl_xor(partial, 4);
      partial += __shfl_xor(partial, 8);
      if (lr == 0) plane[r] = partial;
    }
  }
}

// softmax over S per b, summing the 16 partial-score planes; cov = attn + pc.
__global__ __launch_bounds__(256) void softmax2_kernel(
    const float* __restrict__ scorep, const float* __restrict__ pc,
    float* __restrict__ attn, float* __restrict__ cov) {
  const int b = blockIdx.x, tid = threadIdx.x;
  const int lane = tid & 63, wid = tid >> 6;
  const size_t base = (size_t)b * kS + tid * 8;
  float v[8] = {0.f, 0.f, 0.f, 0.f, 0.f, 0.f, 0.f, 0.f};
  #pragma unroll
  for (int p = 0; p < 16; ++p) {
    const float* s = scorep + (size_t)p * (kB * kS) + base;
    float4 a = *(const float4*)(s);
    float4 c = *(const float4*)(s + 4);
    v[0] += a.x; v[1] += a.y; v[2] += a.z; v[3] += a.w;
    v[4] += c.x; v[5] += c.y; v[6] += c.z; v[7] += c.w;
  }
  float m = v[0];
  #pragma unroll
  for (int i = 1; i < 8; ++i) m = fmaxf(m, v[i]);
  #pragma unroll
  for (int msk = 1; msk < 64; msk <<= 1) m = fmaxf(m, __shfl_xor(m, msk));
  __shared__ float redm[4], reds[4];
  if (lane == 0) redm[wid] = m;
  __syncthreads();
  m = fmaxf(fmaxf(redm[0], redm[1]), fmaxf(redm[2], redm[3]));
  float e[8], sum = 0.f;
  #pragma unroll
  for (int i = 0; i < 8; ++i) { e[i] = __expf(v[i] - m); sum += e[i]; }
  #pragma unroll
  for (int msk = 1; msk < 64; msk <<= 1) sum += __shfl_xor(sum, msk);
  if (lane == 0) reds[wid] = sum;
  __syncthreads();
  sum = reds[0] + reds[1] + reds[2] + reds[3];
  const float inv = 1.0f / sum;
  float pv[8], a[8], c[8];
  const float* p = pc + base;
  *(float4*)(pv) = *(const float4*)(p);
  *(float4*)(pv + 4) = *(const float4*)(p + 4);
  #pragma unroll
  for (int i = 0; i < 8; ++i) { a[i] = e[i] * inv; c[i] = a[i] + pv[i]; }
  *(float4*)(attn + base) = *(float4*)(a);
  *(float4*)(attn + base + 4) = *(float4*)(a + 4);
  *(float4*)(cov + base) = *(float4*)(c);
  *(float4*)(cov + base + 4) = *(float4*)(c + 4);
}

// context from ROW-MAJOR bf16 encR: block = (kt, b); no swizzle, no atomics.
__global__ __launch_bounds__(256) void context2_kernel(
    const unsigned char* __restrict__ encR, const float* __restrict__ attn,
    float* __restrict__ ctx) {
  const int kt = blockIdx.x;             // 64-col slice
  const int b = blockIdx.y;
  const int cg = threadIdx.x & 7;        // 16B piece of the 128B slice
  const int rgrp = threadIdx.x >> 3;     // 32 rows per pass
  float acc8[8];
  #pragma unroll
  for (int j = 0; j < 8; ++j) acc8[j] = 0.f;
  const float* ab = attn + (size_t)b * kS;
  for (int it = 0; it < kS / 32; ++it) {
    const int s = it * 32 + rgrp;
    uint4 v = *(const uint4*)(encR + ((size_t)(b * kS + s)) * 2048 +
                              kt * 128 + cg * 16);
    const float a = ab[s];
    const unsigned int* vw = (const unsigned int*)&v;
    #pragma unroll
    for (int q = 0; q < 4; ++q) {
      acc8[2 * q]     += a * bf2f((unsigned short)(vw[q] & 0xffff));
      acc8[2 * q + 1] += a * bf2f((unsigned short)(vw[q] >> 16));
    }
  }
  __shared__ float red[256 * 8];
  #pragma unroll
  for (int j = 0; j < 8; ++j) red[threadIdx.x * 8 + j] = acc8[j];
  __syncthreads();
  for (int stride = 16; stride > 0; stride >>= 1) {
    if (rgrp < stride) {
      #pragma unroll
      for (int j = 0; j < 8; ++j)
        red[(rgrp * 8 + cg) * 8 + j] += red[((rgrp + stride) * 8 + cg) * 8 + j];
    }
    __syncthreads();
  }
  if (rgrp == 0) {
    #pragma unroll
    for (int j = 0; j < 8; ++j)
      ctx[(size_t)b * kD + kt * 64 + cg * 8 + j] = red[cg * 8 + j];
  }
}

// ---------------- fallback path (round-2 proven kernels, small ws) ----------------

__global__ __launch_bounds__(256) void h2b_kernel(
    const float* __restrict__ dec, const float* __restrict__ Whw,
    const float* __restrict__ Whb, const float* __restrict__ Wsb,
    const float* __restrict__ Wcb, float* __restrict__ h2) {
  const int u = blockIdx.x * 64 + (threadIdx.x & 63);
  const int b = blockIdx.y * 4 + (threadIdx.x >> 6);
  float acc = 0.f;
  const float* dh = dec + b * kD;
  #pragma unroll 8
  for (int d = 0; d < kD; ++d) acc += dh[d] * Whw[(size_t)d * kU + u];
  h2[b * kU + u] = acc + Whb[u] + Wsb[u] + Wcb[u];
}

__global__ __launch_bounds__(256) void tpose_fb_kernel(
    const float* __restrict__ W, unsigned short* __restrict__ out) {
  __shared__ float tile[32][33];
  const int u0 = blockIdx.x * 32, d0 = blockIdx.y * 32;
  const int tx = threadIdx.x & 31, ty = threadIdx.x >> 5;
  #pragma unroll
  for (int i = 0; i < 4; ++i)
    tile[ty + i * 8][tx] = W[(size_t)(d0 + ty + i * 8) * kU + u0 + tx];
  __syncthreads();
  #pragma unroll
  for (int i = 0; i < 4; ++i)
    out[(size_t)(u0 + ty + i * 8) * kD + d0 + tx] = f2bf(tile[tx][ty + i * 8]);
}

__global__ __launch_bounds__(256, 2) void score_gemm_fb_kernel(
    const float* __restrict__ enc, const unsigned short* __restrict__ WsT,
    const float* __restrict__ h2, const float* __restrict__ pc,
    const float* __restrict__ Wcw, const float* __restrict__ Vw,
    float* __restrict__ score) {
  __shared__ __attribute__((aligned(16))) unsigned char smA[128 * 64 * 2];
  __shared__ __attribute__((aligned(16))) unsigned char smB[128 * 64 * 2];
  const int tid = threadIdx.x;
  const int lane = tid & 63;
  const int wid = tid >> 6;
  const int wr = wid >> 1, wc = wid & 1;
  const int mtile = blockIdx.x >> 3, ntile = blockIdx.x & 7;
  const int r0 = mtile * 128, n0 = ntile * 128;
  f32x4 acc[4][4];
  #pragma unroll
  for (int i = 0; i < 4; ++i)
    #pragma unroll
    for (int j = 0; j < 4; ++j) acc[i][j] = (f32x4){0.f, 0.f, 0.f, 0.f};
  const int kqA = tid & 15;
  const int rowA = tid >> 4;
  const int kcB = tid & 7;
  const int nB = tid >> 3;
  float4 aReg[8];
  uint4 bReg[4];
  #pragma unroll
  for (int i = 0; i < 8; ++i)
    aReg[i] = *(const float4*)(enc + (size_t)(r0 + rowA + 16 * i) * kD + kqA * 4);
  #pragma unroll
  for (int i = 0; i < 4; ++i)
    bReg[i] = *(const uint4*)(WsT + (size_t)(n0 + nB + 32 * i) * kD + kcB * 8);
  const int lr = lane & 15, lq = lane >> 4;
  for (int k0 = 0; k0 < kD; k0 += 64) {
    #pragma unroll
    for (int i = 0; i < 8; ++i) {
      const int row = rowA + 16 * i;
      uint2 p;
      p.x = (unsigned)f2bf(aReg[i].x) | ((unsigned)f2bf(aReg[i].y) << 16);
      p.y = (unsigned)f2bf(aReg[i].z) | ((unsigned)f2bf(aReg[i].w) << 16);
      *(uint2*)(smA + row * 128 + ((kqA * 8) ^ ((row & 7) << 4))) = p;
    }
    #pragma unroll
    for (int i = 0; i < 4; ++i) {
      const int n = nB + 32 * i;
      *(uint4*)(smB + n * 128 + ((kcB * 16) ^ ((n & 7) << 4))) = bReg[i];
    }
    __syncthreads();
    if (k0 + 64 < kD) {
      const int kn = k0 + 64;
      #pragma unroll
      for (int i = 0; i < 8; ++i)
        aReg[i] = *(const float4*)(enc + (size_t)(r0 + rowA + 16 * i) * kD + kn + kqA * 4);
      #pragma unroll
      for (int i = 0; i < 4; ++i)
        bReg[i] = *(const uint4*)(WsT + (size_t)(n0 + nB + 32 * i) * kD + kn + kcB * 8);
    }
    #pragma unroll
    for (int ks = 0; ks < 2; ++ks) {
      const int kb = ks * 64 + lq * 16;
      bf16x8 af2[4], bfr[4];
      #pragma unroll
      for (int fm = 0; fm < 4; ++fm) {
        const int row = wr * 64 + fm * 16 + lr;
        af2[fm] = *(const bf16x8*)(smA + row * 128 + (kb ^ ((row & 7) << 4)));
      }
      #pragma unroll
      for (int fn = 0; fn < 4; ++fn) {
        const int n = wc * 64 + fn * 16 + lr;
        bfr[fn] = *(const bf16x8*)(smB + n * 128 + (kb ^ ((n & 7) << 4)));
      }
      #pragma unroll
      for (int fm = 0; fm < 4; ++fm)
        #pragma unroll
        for (int fn = 0; fn < 4; ++fn)
          acc[fm][fn] = MFMA_BF16(af2[fm], bfr[fn], acc[fm][fn]);
    }
    __syncthreads();
  }
  const int bidx = r0 >> 11;
  float hv[4], wv[4], vv[4];
  #pragma unroll
  for (int fn = 0; fn < 4; ++fn) {
    const int u = n0 + wc * 64 + fn * 16 + lr;
    hv[fn] = h2[bidx * kU + u];
    wv[fn] = Wcw[u];
    vv[fn] = Vw[u];
  }
  #pragma unroll
  for (int fm = 0; fm < 4; ++fm) {
    #pragma unroll
    for (int j = 0; j < 4; ++j) {
      const int r = r0 + wr * 64 + fm * 16 + lq * 4 + j;
      const float pcv = pc[r];
      float partial = 0.f;
      #pragma unroll
      for (int fn = 0; fn < 4; ++fn) {
        const float feat = acc[fm][fn][j] + hv[fn] + pcv * wv[fn];
        partial += tanh_fast(feat) * vv[fn];
      }
      partial += __shfl_xor(partial, 1);
      partial += __shfl_xor(partial, 2);
      partial += __shfl_xor(partial, 4);
      partial += __shfl_xor(partial, 8);
      if (lr == 0) atomicAdd(&score[r], partial);
    }
  }
}

__global__ __launch_bounds__(256) void softmax_fb_kernel(
    const float* __restrict__ score, const float* __restrict__ pc,
    float* __restrict__ attn, float* __restrict__ cov) {
  const int b = blockIdx.x, tid = threadIdx.x;
  const int lane = tid & 63, wid = tid >> 6;
  const float* s = score + (size_t)b * kS;
  float v[8];
  *(float4*)(v) = *(const float4*)(s + tid * 8);
  *(float4*)(v + 4) = *(const float4*)(s + tid * 8 + 4);
  float m = v[0];
  #pragma unroll
  for (int i = 1; i < 8; ++i) m = fmaxf(m, v[i]);
  #pragma unroll
  for (int msk = 1; msk < 64; msk <<= 1) m = fmaxf(m, __shfl_xor(m, msk));
  __shared__ float redm[4], reds[4];
  if (lane == 0) redm[wid] = m;
  __syncthreads();
  m = fmaxf(fmaxf(redm[0], redm[1]), fmaxf(redm[2], redm[3]));
  float e[8], sum = 0.f;
  #pragma unroll
  for (int i = 0; i < 8; ++i) { e[i] = __expf(v[i] - m); sum += e[i]; }
  #pragma unroll
  for (int msk = 1; msk < 64; msk <<= 1) sum += __shfl_xor(sum, msk);
  if (lane == 0) reds[wid] = sum;
  __syncthreads();
  sum = reds[0] + reds[1] + reds[2] + reds[3];
  const float inv = 1.0f / sum;
  float pv[8], a[8], c[8];
  const float* p = pc + (size_t)b * kS + tid * 8;
  *(float4*)(pv) = *(const float4*)(p);
  *(float4*)(pv + 4) = *(const float4*)(p + 4);
  #pragma unroll
  for (int i = 0; i < 8; ++i) { a[i] = e[i] * inv; c[i] = a[i] + pv[i]; }
  *(float4*)(attn + (size_t)b * kS + tid * 8) = *(float4*)(a);
  *(float4*)(attn + (size_t)b * kS + tid * 8 + 4) = *(float4*)(a + 4);
  *(float4*)(cov + (size_t)b * kS + tid * 8) = *(float4*)(c);
  *(float4*)(cov + (size_t)b * kS + tid * 8 + 4) = *(float4*)(c + 4);
}

__global__ __launch_bounds__(256) void context_fb_kernel(
    const float* __restrict__ enc, const float* __restrict__ attn,
    float* __restrict__ ctx) {
  const int b = blockIdx.z;
  const int s0 = blockIdx.y * 256;
  const int d = blockIdx.x * 256 + threadIdx.x;
  const float* e = enc + ((size_t)b * kS + s0) * kD + d;
  const float* a = attn + (size_t)b * kS + s0;
  float acc = 0.f;
  #pragma unroll 8
  for (int s = 0; s < 256; ++s) acc += a[s] * e[(size_t)s * kD];
  atomicAdd(&ctx[b * kD + d], acc);
}

}  // namespace

extern "C" void kernel_launch(void* const* d_in, const int* in_sizes, int n_in,
                              void* d_out, int out_size, void* d_ws, size_t ws_size,
                              hipStream_t stream) {
  (void)in_sizes; (void)n_in; (void)out_size;
  const float* dec = (const float*)d_in[0];
  const float* enc = (const float*)d_in[1];
  const float* pc  = (const float*)d_in[4];
  const float* Wsw = (const float*)d_in[5];
  const float* Wsb = (const float*)d_in[6];
  const float* Whw = (const float*)d_in[7];
  const float* Whb = (const float*)d_in[8];
  const float* Wcw = (const float*)d_in[9];
  const float* Wcb = (const float*)d_in[10];
  const float* Vw  = (const float*)d_in[11];

  float* ctx  = (float*)d_out;             // [B, D]
  float* attn = (float*)d_out + kB * kD;   // [B, S]
  float* cov  = attn + kB * kS;            // [B, S, 1]

  unsigned char* ws = (unsigned char*)d_ws;

  const size_t encR_sz = (size_t)kB * kS * kD * 2;   // 128 MiB
  const size_t Bt_sz   = (size_t)kU * kD * 2;        // 2 MiB
  const size_t h2_sz   = (size_t)kB * kU * 4;        // 128 KiB
  const size_t sp_sz   = (size_t)16 * kB * kS * 4;   // 4 MiB
  const size_t need    = encR_sz + Bt_sz + h2_sz + sp_sz;

  if (ws_size >= need) {
    unsigned char* encR = ws;
    unsigned char* Bt   = ws + encR_sz;
    float* h2     = (float*)(ws + encR_sz + Bt_sz);
    float* scorep = (float*)(ws + encR_sz + Bt_sz + h2_sz);

    prep_kernel<<<dim3(kPrepBlocks), 256, 0, stream>>>(
        enc, encR, Wsw, Bt, dec, Whw, Whb, Wsb, Wcb, h2);
    score_gemm4_kernel<<<dim3(kMT * kNT), 512, 0, stream>>>(
        encR, Bt, h2, pc, Wcw, Vw, scorep);
    softmax2_kernel<<<dim3(kB), 256, 0, stream>>>(scorep, pc, attn, cov);
    context2_kernel<<<dim3(kD / 64, kB), 256, 0, stream>>>(encR, attn, ctx);
  } else {
    unsigned short* WsT = (unsigned short*)ws;                       // 2 MiB
    float* h2    = (float*)(ws + (size_t)2 * 1024 * 1024);           // 128 KiB
    float* score = (float*)(ws + (size_t)2 * 1024 * 1024 + 131072);  // 256 KiB
    hipMemsetAsync(score, 0, kB * kS * sizeof(float), stream);
    hipMemsetAsync(ctx, 0, kB * kD * sizeof(float), stream);
    h2b_kernel<<<dim3(kU / 64, kB / 4), 256, 0, stream>>>(dec, Whw, Whb, Wsb, Wcb, h2);
    tpose_fb_kernel<<<dim3(kU / 32, kD / 32), 256, 0, stream>>>(Wsw, WsT);
    score_gemm_fb_kernel<<<dim3(4096), 256, 0, stream>>>(
        enc, WsT, h2, pc, Wcw, Vw, score);
    softmax_fb_kernel<<<dim3(kB), 256, 0, stream>>>(score, pc, attn, cov);
    context_fb_kernel<<<dim3(kD / 256, kS / 256, kB), 256, 0, stream>>>(enc, attn, ctx);
  }
}